// Round 1
// baseline (501.815 us; speedup 1.0000x reference)
//
#include <hip/hip_runtime.h>
#include <hip/hip_bf16.h>

// GAT 2-layer forward for MI355X.
// Pipeline per call (all deterministic, rebuilt each call):
//  1) CSR-by-dst build: zero counts -> histogram -> 3-kernel scan -> scatter
//  2) layer 1: gemm (x@W1) -> att dots -> edge alpha -> node softmax+aggregate(+bias,ReLU)
//  3) layer 2: same with W2, H=1, output straight to d_out (+bias)

#define SLOPE 0.2f
static __device__ __forceinline__ float lrelu(float a) { return a > 0.f ? a : SLOPE * a; }

// ---------------- CSR build ----------------

__global__ void zero_kernel(int* __restrict__ p, int n) {
  int i = blockIdx.x * blockDim.x + threadIdx.x;
  if (i < n) p[i] = 0;
}

__global__ void hist_kernel(const int* __restrict__ dst, int* __restrict__ counts, int E) {
  int e = blockIdx.x * blockDim.x + threadIdx.x;
  if (e < E) atomicAdd(&counts[dst[e]], 1);
}

// scan over counts[N], chunk = 1024 per block (256 threads x 4)
__global__ void scan_partA(const int* __restrict__ counts, int* __restrict__ blockSums, int Nn) {
  __shared__ int sh[256];
  int b = blockIdx.x, t = threadIdx.x;
  int base = b * 1024 + t * 4;
  int s = 0;
#pragma unroll
  for (int j = 0; j < 4; j++) { int i = base + j; if (i < Nn) s += counts[i]; }
  sh[t] = s;
  __syncthreads();
  for (int o = 128; o > 0; o >>= 1) {
    if (t < o) sh[t] += sh[t + o];
    __syncthreads();
  }
  if (t == 0) blockSums[b] = sh[0];
}

__global__ void scan_partB(const int* __restrict__ blockSums, int* __restrict__ blockBase, int NB) {
  // single wave; NB <= 64 (N=50000 -> NB=49)
  int t = threadIdx.x;
  int v = (t < NB) ? blockSums[t] : 0;
  int orig = v;
  for (int o = 1; o < 64; o <<= 1) {
    int u = __shfl_up(v, o);
    if (t >= o) v += u;
  }
  if (t < NB) blockBase[t] = v - orig;  // exclusive prefix
}

__global__ void scan_partC(const int* __restrict__ counts, const int* __restrict__ blockBase,
                           int* __restrict__ offsets, int* __restrict__ cursor, int Nn, int Etot) {
  __shared__ int sh[256];
  int b = blockIdx.x, t = threadIdx.x;
  int base = b * 1024 + t * 4;
  int c[4];
  int s = 0;
#pragma unroll
  for (int j = 0; j < 4; j++) { int i = base + j; c[j] = (i < Nn) ? counts[i] : 0; s += c[j]; }
  sh[t] = s;
  __syncthreads();
  // inclusive Hillis-Steele scan of the 256 thread sums
  for (int o = 1; o < 256; o <<= 1) {
    int v = (t >= o) ? sh[t - o] : 0;
    __syncthreads();
    sh[t] += v;
    __syncthreads();
  }
  int run = sh[t] - s + blockBase[b];
#pragma unroll
  for (int j = 0; j < 4; j++) {
    int i = base + j;
    if (i < Nn) { offsets[i] = run; cursor[i] = run; run += c[j]; }
  }
  if (b == 0 && t == 0) offsets[Nn] = Etot;
}

__global__ void scatter_kernel(const int* __restrict__ src, const int* __restrict__ dst,
                               int* __restrict__ cursor, int* __restrict__ csr_src,
                               int* __restrict__ csr_dst, int E) {
  int e = blockIdx.x * blockDim.x + threadIdx.x;
  if (e < E) {
    int d = dst[e];
    int pos = atomicAdd(&cursor[d], 1);
    csr_src[pos] = src[e];
    csr_dst[pos] = d;
  }
}

// ---------------- dense stages ----------------

// Y[r, t] = sum_k X[r,k] * W[k,t]; block = NC threads, ROWS rows per block.
template <int K, int NC, int ROWS>
__global__ void gemm_rowtile(const float* __restrict__ X, const float* __restrict__ W,
                             float* __restrict__ Y, int Nrows) {
  __shared__ float xs[ROWS][K];
  int r0 = blockIdx.x * ROWS;
  int t = threadIdx.x;
  for (int i = t; i < ROWS * K; i += NC) {
    int r = i / K, k = i - r * K;
    int gr = r0 + r;
    xs[r][k] = (gr < Nrows) ? X[(size_t)gr * K + k] : 0.f;
  }
  __syncthreads();
  float acc[ROWS];
#pragma unroll
  for (int r = 0; r < ROWS; r++) acc[r] = 0.f;
  for (int k = 0; k < K; k++) {
    float w = W[k * NC + t];
#pragma unroll
    for (int r = 0; r < ROWS; r++) acc[r] = fmaf(xs[r][k], w, acc[r]);
  }
#pragma unroll
  for (int r = 0; r < ROWS; r++) {
    int gr = r0 + r;
    if (gr < Nrows) Y[(size_t)gr * NC + t] = acc[r];
  }
}

// a_s[n,h] = sum_c xp[n,h,c]*att_s[h,c]; one 64-lane wave per node.
template <int H>
__global__ void att_kernel(const float* __restrict__ XP, const float* __restrict__ att_s,
                           const float* __restrict__ att_d, float* __restrict__ AS,
                           float* __restrict__ AD, int Nn) {
  int n = blockIdx.x;
  int c = threadIdx.x;  // 0..63
  const float* row = XP + (size_t)n * (H * 64);
#pragma unroll
  for (int h = 0; h < H; h++) {
    float v = row[h * 64 + c];
    float ps = v * att_s[h * 64 + c];
    float pd = v * att_d[h * 64 + c];
    for (int o = 32; o > 0; o >>= 1) {
      ps += __shfl_xor(ps, o);
      pd += __shfl_xor(pd, o);
    }
    if (c == 0) { AS[n * H + h] = ps; AD[n * H + h] = pd; }
  }
}

// per-CSR-slot alpha = leaky_relu(a_s[src] + a_d[dst])
template <int H>
__global__ void alpha_kernel(const int* __restrict__ csr_src, const int* __restrict__ csr_dst,
                             const float* __restrict__ AS, const float* __restrict__ AD,
                             float* __restrict__ ALPHA, int E) {
  int e = blockIdx.x * blockDim.x + threadIdx.x;
  if (e >= E) return;
  int s = csr_src[e], d = csr_dst[e];
#pragma unroll
  for (int h = 0; h < H; h++) {
    float a = AS[s * H + h] + AD[d * H + h];
    ALPHA[(size_t)e * H + h] = lrelu(a);
  }
}

// one block per node; one wave per head; lane = channel.
template <int H, bool RELU>
__global__ void node_kernel(const int* __restrict__ offsets, const int* __restrict__ csr_src,
                            const float* __restrict__ ALPHA, const float* __restrict__ XP,
                            const float* __restrict__ AS, const float* __restrict__ AD,
                            const float* __restrict__ bias, float* __restrict__ OUT, int Nn) {
  constexpr int C = 64;
  constexpr int HC = H * C;
  int n = blockIdx.x;
  int h = threadIdx.x >> 6;
  int lane = threadIdx.x & 63;
  int beg = offsets[n], end = offsets[n + 1];
  int deg = end - beg;

  // self-loop attention logit
  float aself = lrelu(AS[n * H + h] + AD[n * H + h]);

  // pass A: running max then exp-sum (wave-wide reductions per head)
  float m = aself;
  for (int i = lane; i < deg; i += 64) m = fmaxf(m, ALPHA[(size_t)(beg + i) * H + h]);
  for (int o = 32; o > 0; o >>= 1) m = fmaxf(m, __shfl_xor(m, o));

  float z = (lane == 0) ? __expf(aself - m) : 0.f;
  for (int i = lane; i < deg; i += 64) z += __expf(ALPHA[(size_t)(beg + i) * H + h] - m);
  for (int o = 32; o > 0; o >>= 1) z += __shfl_xor(z, o);
  float inv_z = 1.0f / z;

  // pass B: accumulate coef * xp[src]
  float acc = (__expf(aself - m) * inv_z) * XP[(size_t)n * HC + h * C + lane];
  for (int i0 = 0; i0 < deg; i0 += 64) {
    int cnt = min(64, deg - i0);
    int srcv = 0;
    float coefv = 0.f;
    if (lane < cnt) {
      srcv = csr_src[beg + i0 + lane];
      coefv = __expf(ALPHA[(size_t)(beg + i0 + lane) * H + h] - m) * inv_z;
    }
    int j = 0;
    for (; j + 1 < cnt; j += 2) {
      int s0 = __shfl(srcv, j), s1 = __shfl(srcv, j + 1);
      float c0 = __shfl(coefv, j), c1 = __shfl(coefv, j + 1);
      float v0 = XP[(size_t)s0 * HC + h * C + lane];
      float v1 = XP[(size_t)s1 * HC + h * C + lane];
      acc = fmaf(c0, v0, acc);
      acc = fmaf(c1, v1, acc);
    }
    if (j < cnt) {
      int s0 = __shfl(srcv, j);
      float c0 = __shfl(coefv, j);
      acc = fmaf(c0, XP[(size_t)s0 * HC + h * C + lane], acc);
    }
  }
  float r = acc + bias[h * C + lane];
  if (RELU) r = fmaxf(r, 0.f);
  OUT[(size_t)n * HC + h * C + lane] = r;
}

// ---------------- launch ----------------

static inline size_t alignup(size_t x) { return (x + 255) & ~(size_t)255; }

extern "C" void kernel_launch(void* const* d_in, const int* in_sizes, int n_in,
                              void* d_out, int out_size, void* d_ws, size_t ws_size,
                              hipStream_t stream) {
  const float* x    = (const float*)d_in[0];
  const int*   edges= (const int*)d_in[1];
  const float* W1   = (const float*)d_in[2];
  const float* as1w = (const float*)d_in[3];
  const float* ad1w = (const float*)d_in[4];
  const float* b1   = (const float*)d_in[5];
  const float* W2   = (const float*)d_in[6];
  const float* as2w = (const float*)d_in[7];
  const float* ad2w = (const float*)d_in[8];
  const float* b2   = (const float*)d_in[9];

  const int N = in_sizes[0] / 128;   // 50000
  const int E = in_sizes[1] / 2;     // 1600000
  const int* src = edges;
  const int* dst = edges + E;

  // workspace carve-up
  char* p = (char*)d_ws;
  size_t off = 0;
  auto take = [&](size_t bytes) { char* r = p + off; off = alignup(off + bytes); return r; };
  float* xp1   = (float*)take((size_t)N * 128 * 4);
  float* hbuf  = (float*)take((size_t)N * 128 * 4);
  float* xp2   = (float*)take((size_t)N * 64 * 4);
  float* as1   = (float*)take((size_t)N * 2 * 4);
  float* ad1   = (float*)take((size_t)N * 2 * 4);
  float* as2   = (float*)take((size_t)N * 4);
  float* ad2   = (float*)take((size_t)N * 4);
  int* counts  = (int*)take((size_t)N * 4);
  int* offsets = (int*)take((size_t)(N + 1) * 4);
  int* cursor  = (int*)take((size_t)N * 4);
  int* bsum    = (int*)take(64 * 4);
  int* bbase   = (int*)take(64 * 4);
  int* csr_src = (int*)take((size_t)E * 4);
  int* csr_dst = (int*)take((size_t)E * 4);
  float* alphaP= (float*)take((size_t)E * 2 * 4);
  (void)ws_size;

  const int TB = 256;
  const int NB = (N + 1023) / 1024;          // scan blocks (<=64)
  const int EB = (E + TB - 1) / TB;

  // --- CSR build ---
  zero_kernel<<<(N + TB - 1) / TB, TB, 0, stream>>>(counts, N);
  hist_kernel<<<EB, TB, 0, stream>>>(dst, counts, E);
  scan_partA<<<NB, 256, 0, stream>>>(counts, bsum, N);
  scan_partB<<<1, 64, 0, stream>>>(bsum, bbase, NB);
  scan_partC<<<NB, 256, 0, stream>>>(counts, bbase, offsets, cursor, N, E);
  scatter_kernel<<<EB, TB, 0, stream>>>(src, dst, cursor, csr_src, csr_dst, E);

  // --- layer 1 (H=2, C=64, ReLU) ---
  gemm_rowtile<128, 128, 8><<<(N + 7) / 8, 128, 0, stream>>>(x, W1, xp1, N);
  att_kernel<2><<<N, 64, 0, stream>>>(xp1, as1w, ad1w, as1, ad1, N);
  alpha_kernel<2><<<EB, TB, 0, stream>>>(csr_src, csr_dst, as1, ad1, alphaP, E);
  node_kernel<2, true><<<N, 128, 0, stream>>>(offsets, csr_src, alphaP, xp1, as1, ad1, b1, hbuf, N);

  // --- layer 2 (H=1, C=64) ---
  gemm_rowtile<128, 64, 8><<<(N + 7) / 8, 64, 0, stream>>>(hbuf, W2, xp2, N);
  att_kernel<1><<<N, 64, 0, stream>>>(xp2, as2w, ad2w, as2, ad2, N);
  alpha_kernel<1><<<EB, TB, 0, stream>>>(csr_src, csr_dst, as2, ad2, alphaP, E);
  node_kernel<1, false><<<N, 64, 0, stream>>>(offsets, csr_src, alphaP, xp2, as2, ad2, b2, (float*)d_out, N);
}

// Round 2
// 451.722 us; speedup vs baseline: 1.1109x; 1.1109x over previous
//
#include <hip/hip_runtime.h>
#include <hip/hip_bf16.h>

// GAT 2-layer forward for MI355X — round 2.
// Changes vs round 1:
//  - node_kernel: single-pass unnormalized softmax (no max pass: logits bounded),
//    alpha computed inline from AS/AD (alpha_kernel removed), float4 gather with
//    4 edges per wave-iteration (16 lanes x float4 = 1KB per load instr).
//  - att dots (AS/AD) fused into the GEMM epilogue via wave-shuffle reduction.
//  - CSR build no longer stores csr_dst.

#define SLOPE 0.2f
static __device__ __forceinline__ float lrelu(float a) { return a > 0.f ? a : SLOPE * a; }

// ---------------- CSR build ----------------

__global__ void zero_kernel(int* __restrict__ p, int n) {
  int i = blockIdx.x * blockDim.x + threadIdx.x;
  if (i < n) p[i] = 0;
}

__global__ void hist_kernel(const int* __restrict__ dst, int* __restrict__ counts, int E) {
  int e = blockIdx.x * blockDim.x + threadIdx.x;
  if (e < E) atomicAdd(&counts[dst[e]], 1);
}

__global__ void scan_partA(const int* __restrict__ counts, int* __restrict__ blockSums, int Nn) {
  __shared__ int sh[256];
  int b = blockIdx.x, t = threadIdx.x;
  int base = b * 1024 + t * 4;
  int s = 0;
#pragma unroll
  for (int j = 0; j < 4; j++) { int i = base + j; if (i < Nn) s += counts[i]; }
  sh[t] = s;
  __syncthreads();
  for (int o = 128; o > 0; o >>= 1) {
    if (t < o) sh[t] += sh[t + o];
    __syncthreads();
  }
  if (t == 0) blockSums[b] = sh[0];
}

__global__ void scan_partB(const int* __restrict__ blockSums, int* __restrict__ blockBase, int NB) {
  int t = threadIdx.x;
  int v = (t < NB) ? blockSums[t] : 0;
  int orig = v;
  for (int o = 1; o < 64; o <<= 1) {
    int u = __shfl_up(v, o);
    if (t >= o) v += u;
  }
  if (t < NB) blockBase[t] = v - orig;
}

__global__ void scan_partC(const int* __restrict__ counts, const int* __restrict__ blockBase,
                           int* __restrict__ offsets, int* __restrict__ cursor, int Nn, int Etot) {
  __shared__ int sh[256];
  int b = blockIdx.x, t = threadIdx.x;
  int base = b * 1024 + t * 4;
  int c[4];
  int s = 0;
#pragma unroll
  for (int j = 0; j < 4; j++) { int i = base + j; c[j] = (i < Nn) ? counts[i] : 0; s += c[j]; }
  sh[t] = s;
  __syncthreads();
  for (int o = 1; o < 256; o <<= 1) {
    int v = (t >= o) ? sh[t - o] : 0;
    __syncthreads();
    sh[t] += v;
    __syncthreads();
  }
  int run = sh[t] - s + blockBase[b];
#pragma unroll
  for (int j = 0; j < 4; j++) {
    int i = base + j;
    if (i < Nn) { offsets[i] = run; cursor[i] = run; run += c[j]; }
  }
  if (b == 0 && t == 0) offsets[Nn] = Etot;
}

__global__ void scatter_kernel(const int* __restrict__ src, const int* __restrict__ dst,
                               int* __restrict__ cursor, int* __restrict__ csr_src, int E) {
  int e = blockIdx.x * blockDim.x + threadIdx.x;
  if (e < E) {
    int d = dst[e];
    int pos = atomicAdd(&cursor[d], 1);
    csr_src[pos] = src[e];
  }
}

// ---------------- GEMM + fused attention dots ----------------

// Y[r,t] = sum_k X[r,k]*W[k,t]; also AS[n,h]=sum_c Y[n,h,c]*att_s[h,c] (wave=head).
// Block = NC threads; ROWS rows per block; N must be divisible by ROWS (50000/16=3125).
template <int K, int NC, int ROWS, int H>
__global__ void gemm_att(const float* __restrict__ X, const float* __restrict__ W,
                         const float* __restrict__ att_s, const float* __restrict__ att_d,
                         float* __restrict__ Y, float* __restrict__ AS, float* __restrict__ AD,
                         int Nrows) {
  __shared__ float xs[ROWS * K];
  int r0 = blockIdx.x * ROWS;
  int t = threadIdx.x;
  int h = t >> 6;
  int lane = t & 63;

  // stage ROWS x K with float4
  const float4* X4 = (const float4*)(X + (size_t)r0 * K);
  float4* xs4 = (float4*)xs;
  for (int i = t; i < ROWS * K / 4; i += NC) xs4[i] = X4[i];
  __syncthreads();

  float acc[ROWS];
#pragma unroll
  for (int r = 0; r < ROWS; r++) acc[r] = 0.f;
  for (int k = 0; k < K; k++) {
    float w = W[k * NC + t];
#pragma unroll
    for (int r = 0; r < ROWS; r++) acc[r] = fmaf(xs[r * K + k], w, acc[r]);
  }

  float asw = att_s[t];
  float adw = att_d[t];
#pragma unroll
  for (int r = 0; r < ROWS; r++) {
    Y[(size_t)(r0 + r) * NC + t] = acc[r];
    float ps = acc[r] * asw;
    float pd = acc[r] * adw;
    for (int o = 32; o > 0; o >>= 1) {
      ps += __shfl_xor(ps, o);
      pd += __shfl_xor(pd, o);
    }
    if (lane == 0) {
      AS[(r0 + r) * H + h] = ps;
      AD[(r0 + r) * H + h] = pd;
    }
  }
}

// ---------------- node softmax + aggregate ----------------

// One block per node; wave = head; within wave: 4 groups of 16 lanes, each group
// handles one edge per inner iteration with float4 channel loads.
template <int H, bool RELU>
__global__ void node_kernel(const int* __restrict__ offsets, const int* __restrict__ csr_src,
                            const float* __restrict__ AS, const float* __restrict__ AD,
                            const float* __restrict__ XP, const float* __restrict__ bias,
                            float* __restrict__ OUT, int Nn) {
  constexpr int C = 64;
  constexpr int HC4 = H * C / 4;  // float4 row stride
  int n = blockIdx.x;
  int h = threadIdx.x >> 6;
  int lane = threadIdx.x & 63;
  int g = lane >> 4;    // edge group 0..3
  int sub = lane & 15;  // float4 channel slot

  int beg = offsets[n], end = offsets[n + 1];
  int deg = end - beg;

  float ad_n = AD[n * H + h];
  const float4* XP4 = (const float4*)XP;

  float4 acc = make_float4(0.f, 0.f, 0.f, 0.f);
  float z = 0.f;

  // self-loop (group 0 accumulates vector part; lane 0 accumulates z)
  float e_self = __expf(lrelu(AS[n * H + h] + ad_n));
  if (g == 0) {
    float4 v = XP4[(size_t)n * HC4 + h * 16 + sub];
    acc.x = e_self * v.x; acc.y = e_self * v.y; acc.z = e_self * v.z; acc.w = e_self * v.w;
  }
  if (lane == 0) z = e_self;

  for (int i0 = 0; i0 < deg; i0 += 64) {
    int cnt = min(64, deg - i0);
    int srcv = 0;
    float ev = 0.f;
    if (lane < cnt) {
      srcv = csr_src[beg + i0 + lane];
      ev = __expf(lrelu(AS[srcv * H + h] + ad_n));
    }
    z += ev;
    int j = 0;
    for (; j + 4 <= cnt; j += 4) {
      int idx = j + g;
      int s = __shfl(srcv, idx);
      float e = __shfl(ev, idx);
      float4 v = XP4[(size_t)s * HC4 + h * 16 + sub];
      acc.x = fmaf(e, v.x, acc.x);
      acc.y = fmaf(e, v.y, acc.y);
      acc.z = fmaf(e, v.z, acc.z);
      acc.w = fmaf(e, v.w, acc.w);
    }
    if (j < cnt) {  // wave-uniform branch; 1..3 remainder edges
      int idx = j + g;
      int s = __shfl(srcv, idx & 63);
      float e = __shfl(ev, idx & 63);
      if (idx < cnt) {
        float4 v = XP4[(size_t)s * HC4 + h * 16 + sub];
        acc.x = fmaf(e, v.x, acc.x);
        acc.y = fmaf(e, v.y, acc.y);
        acc.z = fmaf(e, v.z, acc.z);
        acc.w = fmaf(e, v.w, acc.w);
      }
    }
  }

  // reduce acc across the 4 groups
#pragma unroll
  for (int o = 32; o >= 16; o >>= 1) {
    acc.x += __shfl_xor(acc.x, o);
    acc.y += __shfl_xor(acc.y, o);
    acc.z += __shfl_xor(acc.z, o);
    acc.w += __shfl_xor(acc.w, o);
  }
  // reduce z across the wave
  for (int o = 32; o > 0; o >>= 1) z += __shfl_xor(z, o);
  float inv = 1.0f / z;

  if (g == 0) {
    float4 b4 = ((const float4*)bias)[h * 16 + sub];
    float4 r;
    r.x = fmaf(acc.x, inv, b4.x);
    r.y = fmaf(acc.y, inv, b4.y);
    r.z = fmaf(acc.z, inv, b4.z);
    r.w = fmaf(acc.w, inv, b4.w);
    if (RELU) {
      r.x = fmaxf(r.x, 0.f); r.y = fmaxf(r.y, 0.f);
      r.z = fmaxf(r.z, 0.f); r.w = fmaxf(r.w, 0.f);
    }
    ((float4*)OUT)[(size_t)n * HC4 + h * 16 + sub] = r;
  }
}

// ---------------- launch ----------------

static inline size_t alignup(size_t x) { return (x + 255) & ~(size_t)255; }

extern "C" void kernel_launch(void* const* d_in, const int* in_sizes, int n_in,
                              void* d_out, int out_size, void* d_ws, size_t ws_size,
                              hipStream_t stream) {
  const float* x    = (const float*)d_in[0];
  const int*   edges= (const int*)d_in[1];
  const float* W1   = (const float*)d_in[2];
  const float* as1w = (const float*)d_in[3];
  const float* ad1w = (const float*)d_in[4];
  const float* b1   = (const float*)d_in[5];
  const float* W2   = (const float*)d_in[6];
  const float* as2w = (const float*)d_in[7];
  const float* ad2w = (const float*)d_in[8];
  const float* b2   = (const float*)d_in[9];

  const int N = in_sizes[0] / 128;   // 50000
  const int E = in_sizes[1] / 2;     // 1600000
  const int* src = edges;
  const int* dst = edges + E;

  char* p = (char*)d_ws;
  size_t off = 0;
  auto take = [&](size_t bytes) { char* r = p + off; off = alignup(off + bytes); return r; };
  float* xp1   = (float*)take((size_t)N * 128 * 4);
  float* hbuf  = (float*)take((size_t)N * 128 * 4);
  float* xp2   = (float*)take((size_t)N * 64 * 4);
  float* as1   = (float*)take((size_t)N * 2 * 4);
  float* ad1   = (float*)take((size_t)N * 2 * 4);
  float* as2   = (float*)take((size_t)N * 4);
  float* ad2   = (float*)take((size_t)N * 4);
  int* counts  = (int*)take((size_t)N * 4);
  int* offsets = (int*)take((size_t)(N + 1) * 4);
  int* cursor  = (int*)take((size_t)N * 4);
  int* bsum    = (int*)take(64 * 4);
  int* bbase   = (int*)take(64 * 4);
  int* csr_src = (int*)take((size_t)E * 4);
  (void)ws_size;

  const int TB = 256;
  const int NB = (N + 1023) / 1024;
  const int EB = (E + TB - 1) / TB;

  // CSR build (by dst; self-loops handled analytically in node_kernel)
  zero_kernel<<<(N + TB - 1) / TB, TB, 0, stream>>>(counts, N);
  hist_kernel<<<EB, TB, 0, stream>>>(dst, counts, E);
  scan_partA<<<NB, 256, 0, stream>>>(counts, bsum, N);
  scan_partB<<<1, 64, 0, stream>>>(bsum, bbase, NB);
  scan_partC<<<NB, 256, 0, stream>>>(counts, bbase, offsets, cursor, N, E);
  scatter_kernel<<<EB, TB, 0, stream>>>(src, dst, cursor, csr_src, E);

  // layer 1 (H=2, C=64, ReLU)
  gemm_att<128, 128, 16, 2><<<N / 16, 128, 0, stream>>>(x, W1, as1w, ad1w, xp1, as1, ad1, N);
  node_kernel<2, true><<<N, 128, 0, stream>>>(offsets, csr_src, as1, ad1, xp1, b1, hbuf, N);

  // layer 2 (H=1, C=64)
  gemm_att<128, 64, 16, 1><<<N / 16, 64, 0, stream>>>(hbuf, W2, as2w, ad2w, xp2, as2, ad2, N);
  node_kernel<1, false><<<N, 64, 0, stream>>>(offsets, csr_src, as2, ad2, xp2, b2, (float*)d_out, N);
}

// Round 3
// 302.576 us; speedup vs baseline: 1.6585x; 1.4929x over previous
//
#include <hip/hip_runtime.h>
#include <hip/hip_bf16.h>

// GAT 2-layer forward for MI355X — round 3.
// Change vs round 2: CSR build rewritten as a two-level bucket sort so that ALL
// global writes are coalesced (round-2 scatter_kernel wrote 101 MB of partial
// cache lines for a 6.4 MB array). Buckets = dst>>8 (256 nodes each); edges are
// packed into 4 B as (bucket<<24)|(src<<8)|(dst&255) (valid for N<=65536).
// Random scatter now happens only inside LDS.

#define SLOPE 0.2f
static __device__ __forceinline__ float lrelu(float a) { return a > 0.f ? a : SLOPE * a; }

#define NBK_MAX 256  // max buckets (N <= 65536)

// ---------------- CSR build (bucketed) ----------------

__global__ void zero_small(int* __restrict__ p, int n) {
  int i = blockIdx.x * blockDim.x + threadIdx.x;
  if (i < n) p[i] = 0;
}

// LDS-aggregated histogram of dst>>8
__global__ void bucket_hist(const int* __restrict__ dst, int* __restrict__ bucket_count,
                            int E, int nbk) {
  __shared__ int h[NBK_MAX];
  for (int i = threadIdx.x; i < nbk; i += blockDim.x) h[i] = 0;
  __syncthreads();
  int stride = gridDim.x * blockDim.x;
  for (int e = blockIdx.x * blockDim.x + threadIdx.x; e < E; e += stride)
    atomicAdd(&h[dst[e] >> 8], 1);
  __syncthreads();
  for (int i = threadIdx.x; i < nbk; i += blockDim.x)
    if (h[i]) atomicAdd(&bucket_count[i], h[i]);
}

// single block: exclusive scan over bucket counts -> bases + cursors
__global__ void bucket_scan(const int* __restrict__ bucket_count, int* __restrict__ bucket_base,
                            int* __restrict__ bucket_cursor, int nbk, int Etot) {
  __shared__ int sh[256];
  int t = threadIdx.x;
  int v = (t < nbk) ? bucket_count[t] : 0;
  sh[t] = v;
  __syncthreads();
  for (int o = 1; o < 256; o <<= 1) {
    int u = (t >= o) ? sh[t - o] : 0;
    __syncthreads();
    sh[t] += u;
    __syncthreads();
  }
  int excl = sh[t] - v;
  if (t < nbk) { bucket_base[t] = excl; bucket_cursor[t] = excl; }
  if (t == 0) bucket_base[nbk] = Etot;
}

// bin pass: CHUNK edges per block; LDS-sort by bucket; coalesced chunk writes.
template <int CHUNK>  // 8192 = 256 threads x 32
__global__ void bin_kernel(const int* __restrict__ src, const int* __restrict__ dst,
                           int* __restrict__ bucket_cursor, unsigned int* __restrict__ binned,
                           int E, int nbk) {
  constexpr int PT = CHUNK / 256;
  __shared__ int hist[NBK_MAX];
  __shared__ int lbase[NBK_MAX];
  __shared__ int lcur[NBK_MAX];
  __shared__ int gpos[NBK_MAX];
  __shared__ unsigned int stage[CHUNK];
  __shared__ int sh[256];
  int t = threadIdx.x;
  int e0 = blockIdx.x * CHUNK;
  int cnt = min(CHUNK, E - e0);

  for (int i = t; i < nbk; i += 256) hist[i] = 0;
  __syncthreads();

  unsigned int pk[PT];
#pragma unroll
  for (int i = 0; i < PT; i++) {
    int e = e0 + t + i * 256;
    if (e < E) {
      int s = src[e], d = dst[e];
      int b = d >> 8;
      pk[i] = ((unsigned)b << 24) | ((unsigned)s << 8) | (unsigned)(d & 255);
      atomicAdd(&hist[b], 1);
    } else {
      pk[i] = 0xFFFFFFFFu;
    }
  }
  __syncthreads();

  // exclusive scan of hist over 256 slots
  int hv = (t < nbk) ? hist[t] : 0;
  sh[t] = hv;
  __syncthreads();
  for (int o = 1; o < 256; o <<= 1) {
    int u = (t >= o) ? sh[t - o] : 0;
    __syncthreads();
    sh[t] += u;
    __syncthreads();
  }
  if (t < nbk) {
    lbase[t] = sh[t] - hv;
    lcur[t] = sh[t] - hv;
    gpos[t] = hv ? atomicAdd(&bucket_cursor[t], hv) : 0;
  }
  __syncthreads();

  // local scatter into stage (sorted by bucket)
#pragma unroll
  for (int i = 0; i < PT; i++) {
    if (pk[i] != 0xFFFFFFFFu) {
      int b = pk[i] >> 24;
      int lp = atomicAdd(&lcur[b], 1);
      stage[lp] = pk[i];
    }
  }
  __syncthreads();

  // coalesced writes: bucket-contiguous runs
  for (int i = t; i < cnt; i += 256) {
    unsigned int v = stage[i];
    int b = v >> 24;
    binned[gpos[b] + (i - lbase[b])] = v;
  }
}

// build pass: one block per bucket. LDS node-hist + scan -> offsets (coalesced),
// LDS scatter of src -> sequential csr_src write.
template <int CAP>  // 12288 (uniform-degree max bucket ~8700; safe margin)
__global__ void build_kernel(const unsigned int* __restrict__ binned,
                             const int* __restrict__ bucket_base, int* __restrict__ offsets,
                             int* __restrict__ csr_src, int Nn, int Etot, int nbk) {
  __shared__ int nhist[256];
  __shared__ int sh[256];
  __shared__ int lcur[256];
  __shared__ unsigned short stage[CAP];
  int b = blockIdx.x;
  int t = threadIdx.x;
  int base = bucket_base[b];
  int sz = bucket_base[b + 1] - base;

  nhist[t] = 0;
  __syncthreads();
  for (int i = t; i < sz; i += 256) atomicAdd(&nhist[binned[base + i] & 255], 1);
  __syncthreads();

  int hv = nhist[t];
  sh[t] = hv;
  __syncthreads();
  for (int o = 1; o < 256; o <<= 1) {
    int u = (t >= o) ? sh[t - o] : 0;
    __syncthreads();
    sh[t] += u;
    __syncthreads();
  }
  int excl = sh[t] - hv;
  int node = (b << 8) + t;
  if (node < Nn) offsets[node] = base + excl;
  if (b == nbk - 1 && t == 0) offsets[Nn] = Etot;
  lcur[t] = excl;
  __syncthreads();

  if (sz <= CAP) {
    for (int i = t; i < sz; i += 256) {
      unsigned int v = binned[base + i];
      int lp = atomicAdd(&lcur[v & 255], 1);
      stage[lp] = (unsigned short)((v >> 8) & 0xFFFFu);
    }
    __syncthreads();
    for (int i = t; i < sz; i += 256) csr_src[base + i] = (int)stage[i];
  } else {  // fallback (never hit for uniform random graphs)
    for (int i = t; i < sz; i += 256) {
      unsigned int v = binned[base + i];
      int lp = atomicAdd(&lcur[v & 255], 1);
      csr_src[base + lp] = (int)((v >> 8) & 0xFFFFu);
    }
  }
}

// ---------------- GEMM + fused attention dots ----------------

template <int K, int NC, int ROWS, int H>
__global__ void gemm_att(const float* __restrict__ X, const float* __restrict__ W,
                         const float* __restrict__ att_s, const float* __restrict__ att_d,
                         float* __restrict__ Y, float* __restrict__ AS, float* __restrict__ AD,
                         int Nrows) {
  __shared__ float xs[ROWS * K];
  int r0 = blockIdx.x * ROWS;
  int t = threadIdx.x;
  int h = t >> 6;
  int lane = t & 63;

  const float4* X4 = (const float4*)(X + (size_t)r0 * K);
  float4* xs4 = (float4*)xs;
  for (int i = t; i < ROWS * K / 4; i += NC) xs4[i] = X4[i];
  __syncthreads();

  float acc[ROWS];
#pragma unroll
  for (int r = 0; r < ROWS; r++) acc[r] = 0.f;
  for (int k = 0; k < K; k++) {
    float w = W[k * NC + t];
#pragma unroll
    for (int r = 0; r < ROWS; r++) acc[r] = fmaf(xs[r * K + k], w, acc[r]);
  }

  float asw = att_s[t];
  float adw = att_d[t];
#pragma unroll
  for (int r = 0; r < ROWS; r++) {
    Y[(size_t)(r0 + r) * NC + t] = acc[r];
    float ps = acc[r] * asw;
    float pd = acc[r] * adw;
    for (int o = 32; o > 0; o >>= 1) {
      ps += __shfl_xor(ps, o);
      pd += __shfl_xor(pd, o);
    }
    if (lane == 0) {
      AS[(r0 + r) * H + h] = ps;
      AD[(r0 + r) * H + h] = pd;
    }
  }
}

// ---------------- node softmax + aggregate ----------------

template <int H, bool RELU>
__global__ void node_kernel(const int* __restrict__ offsets, const int* __restrict__ csr_src,
                            const float* __restrict__ AS, const float* __restrict__ AD,
                            const float* __restrict__ XP, const float* __restrict__ bias,
                            float* __restrict__ OUT, int Nn) {
  constexpr int C = 64;
  constexpr int HC4 = H * C / 4;
  int n = blockIdx.x;
  int h = threadIdx.x >> 6;
  int lane = threadIdx.x & 63;
  int g = lane >> 4;
  int sub = lane & 15;

  int beg = offsets[n], end = offsets[n + 1];
  int deg = end - beg;

  float ad_n = AD[n * H + h];
  const float4* XP4 = (const float4*)XP;

  float4 acc = make_float4(0.f, 0.f, 0.f, 0.f);
  float z = 0.f;

  float e_self = __expf(lrelu(AS[n * H + h] + ad_n));
  if (g == 0) {
    float4 v = XP4[(size_t)n * HC4 + h * 16 + sub];
    acc.x = e_self * v.x; acc.y = e_self * v.y; acc.z = e_self * v.z; acc.w = e_self * v.w;
  }
  if (lane == 0) z = e_self;

  for (int i0 = 0; i0 < deg; i0 += 64) {
    int cnt = min(64, deg - i0);
    int srcv = 0;
    float ev = 0.f;
    if (lane < cnt) {
      srcv = csr_src[beg + i0 + lane];
      ev = __expf(lrelu(AS[srcv * H + h] + ad_n));
    }
    z += ev;
    int j = 0;
    for (; j + 4 <= cnt; j += 4) {
      int idx = j + g;
      int s = __shfl(srcv, idx);
      float e = __shfl(ev, idx);
      float4 v = XP4[(size_t)s * HC4 + h * 16 + sub];
      acc.x = fmaf(e, v.x, acc.x);
      acc.y = fmaf(e, v.y, acc.y);
      acc.z = fmaf(e, v.z, acc.z);
      acc.w = fmaf(e, v.w, acc.w);
    }
    if (j < cnt) {
      int idx = j + g;
      int s = __shfl(srcv, idx & 63);
      float e = __shfl(ev, idx & 63);
      if (idx < cnt) {
        float4 v = XP4[(size_t)s * HC4 + h * 16 + sub];
        acc.x = fmaf(e, v.x, acc.x);
        acc.y = fmaf(e, v.y, acc.y);
        acc.z = fmaf(e, v.z, acc.z);
        acc.w = fmaf(e, v.w, acc.w);
      }
    }
  }

#pragma unroll
  for (int o = 32; o >= 16; o >>= 1) {
    acc.x += __shfl_xor(acc.x, o);
    acc.y += __shfl_xor(acc.y, o);
    acc.z += __shfl_xor(acc.z, o);
    acc.w += __shfl_xor(acc.w, o);
  }
  for (int o = 32; o > 0; o >>= 1) z += __shfl_xor(z, o);
  float inv = 1.0f / z;

  if (g == 0) {
    float4 b4 = ((const float4*)bias)[h * 16 + sub];
    float4 r;
    r.x = fmaf(acc.x, inv, b4.x);
    r.y = fmaf(acc.y, inv, b4.y);
    r.z = fmaf(acc.z, inv, b4.z);
    r.w = fmaf(acc.w, inv, b4.w);
    if (RELU) {
      r.x = fmaxf(r.x, 0.f); r.y = fmaxf(r.y, 0.f);
      r.z = fmaxf(r.z, 0.f); r.w = fmaxf(r.w, 0.f);
    }
    ((float4*)OUT)[(size_t)n * HC4 + h * 16 + sub] = r;
  }
}

// ---------------- launch ----------------

static inline size_t alignup(size_t x) { return (x + 255) & ~(size_t)255; }

extern "C" void kernel_launch(void* const* d_in, const int* in_sizes, int n_in,
                              void* d_out, int out_size, void* d_ws, size_t ws_size,
                              hipStream_t stream) {
  const float* x    = (const float*)d_in[0];
  const int*   edges= (const int*)d_in[1];
  const float* W1   = (const float*)d_in[2];
  const float* as1w = (const float*)d_in[3];
  const float* ad1w = (const float*)d_in[4];
  const float* b1   = (const float*)d_in[5];
  const float* W2   = (const float*)d_in[6];
  const float* as2w = (const float*)d_in[7];
  const float* ad2w = (const float*)d_in[8];
  const float* b2   = (const float*)d_in[9];

  const int N = in_sizes[0] / 128;   // 50000
  const int E = in_sizes[1] / 2;     // 1600000
  const int* src = edges;
  const int* dst = edges + E;
  const int nbk = (N + 255) >> 8;    // 196 buckets

  char* p = (char*)d_ws;
  size_t off = 0;
  auto take = [&](size_t bytes) { char* r = p + off; off = alignup(off + bytes); return r; };
  float* xp1   = (float*)take((size_t)N * 128 * 4);
  float* hbuf  = (float*)take((size_t)N * 128 * 4);
  float* xp2   = (float*)take((size_t)N * 64 * 4);
  float* as1   = (float*)take((size_t)N * 2 * 4);
  float* ad1   = (float*)take((size_t)N * 2 * 4);
  float* as2   = (float*)take((size_t)N * 4);
  float* ad2   = (float*)take((size_t)N * 4);
  int* offsets = (int*)take((size_t)(N + 1) * 4);
  int* csr_src = (int*)take((size_t)E * 4);
  unsigned int* binned = (unsigned int*)take((size_t)E * 4);
  int* bcount  = (int*)take((size_t)(nbk + 1) * 4);
  int* bbase   = (int*)take((size_t)(nbk + 1) * 4);
  int* bcursor = (int*)take((size_t)(nbk + 1) * 4);
  (void)ws_size;

  constexpr int CHUNK = 8192;
  const int binBlocks = (E + CHUNK - 1) / CHUNK;

  // CSR build (bucketed two-level sort; all global writes coalesced)
  zero_small<<<1, 256, 0, stream>>>(bcount, nbk);
  bucket_hist<<<392, 256, 0, stream>>>(dst, bcount, E, nbk);
  bucket_scan<<<1, 256, 0, stream>>>(bcount, bbase, bcursor, nbk, E);
  bin_kernel<CHUNK><<<binBlocks, 256, 0, stream>>>(src, dst, bcursor, binned, E, nbk);
  build_kernel<12288><<<nbk, 256, 0, stream>>>(binned, bbase, offsets, csr_src, N, E, nbk);

  // layer 1 (H=2, C=64, ReLU)
  gemm_att<128, 128, 16, 2><<<N / 16, 128, 0, stream>>>(x, W1, as1w, ad1w, xp1, as1, ad1, N);
  node_kernel<2, true><<<N, 128, 0, stream>>>(offsets, csr_src, as1, ad1, xp1, b1, hbuf, N);

  // layer 2 (H=1, C=64)
  gemm_att<128, 64, 16, 1><<<N / 16, 64, 0, stream>>>(hbuf, W2, as2w, ad2w, xp2, as2, ad2, N);
  node_kernel<1, false><<<N, 64, 0, stream>>>(offsets, csr_src, as2, ad2, xp2, b2, (float*)d_out, N);
}

// Round 4
// 297.148 us; speedup vs baseline: 1.6888x; 1.0183x over previous
//
#include <hip/hip_runtime.h>
#include <hip/hip_bf16.h>

// GAT 2-layer forward for MI355X — round 4.
// Change vs round 3: node_kernel inner gather unrolled to keep 4 independent
// global_load_dwordx4 in flight per wave (16 edges/iter, 4 accumulators),
// attacking the latency-bound single-outstanding-load regime seen in r3
// (VALUBusy 26%, hbm 46%, 1 load per vmcnt(0)).

#define SLOPE 0.2f
static __device__ __forceinline__ float lrelu(float a) { return a > 0.f ? a : SLOPE * a; }

#define NBK_MAX 256  // max buckets (N <= 65536)

// ---------------- CSR build (bucketed) ----------------

__global__ void zero_small(int* __restrict__ p, int n) {
  int i = blockIdx.x * blockDim.x + threadIdx.x;
  if (i < n) p[i] = 0;
}

__global__ void bucket_hist(const int* __restrict__ dst, int* __restrict__ bucket_count,
                            int E, int nbk) {
  __shared__ int h[NBK_MAX];
  for (int i = threadIdx.x; i < nbk; i += blockDim.x) h[i] = 0;
  __syncthreads();
  int stride = gridDim.x * blockDim.x;
  for (int e = blockIdx.x * blockDim.x + threadIdx.x; e < E; e += stride)
    atomicAdd(&h[dst[e] >> 8], 1);
  __syncthreads();
  for (int i = threadIdx.x; i < nbk; i += blockDim.x)
    if (h[i]) atomicAdd(&bucket_count[i], h[i]);
}

__global__ void bucket_scan(const int* __restrict__ bucket_count, int* __restrict__ bucket_base,
                            int* __restrict__ bucket_cursor, int nbk, int Etot) {
  __shared__ int sh[256];
  int t = threadIdx.x;
  int v = (t < nbk) ? bucket_count[t] : 0;
  sh[t] = v;
  __syncthreads();
  for (int o = 1; o < 256; o <<= 1) {
    int u = (t >= o) ? sh[t - o] : 0;
    __syncthreads();
    sh[t] += u;
    __syncthreads();
  }
  int excl = sh[t] - v;
  if (t < nbk) { bucket_base[t] = excl; bucket_cursor[t] = excl; }
  if (t == 0) bucket_base[nbk] = Etot;
}

template <int CHUNK>  // 8192 = 256 threads x 32
__global__ void bin_kernel(const int* __restrict__ src, const int* __restrict__ dst,
                           int* __restrict__ bucket_cursor, unsigned int* __restrict__ binned,
                           int E, int nbk) {
  constexpr int PT = CHUNK / 256;
  __shared__ int hist[NBK_MAX];
  __shared__ int lbase[NBK_MAX];
  __shared__ int lcur[NBK_MAX];
  __shared__ int gpos[NBK_MAX];
  __shared__ unsigned int stage[CHUNK];
  __shared__ int sh[256];
  int t = threadIdx.x;
  int e0 = blockIdx.x * CHUNK;
  int cnt = min(CHUNK, E - e0);

  for (int i = t; i < nbk; i += 256) hist[i] = 0;
  __syncthreads();

  unsigned int pk[PT];
#pragma unroll
  for (int i = 0; i < PT; i++) {
    int e = e0 + t + i * 256;
    if (e < E) {
      int s = src[e], d = dst[e];
      int b = d >> 8;
      pk[i] = ((unsigned)b << 24) | ((unsigned)s << 8) | (unsigned)(d & 255);
      atomicAdd(&hist[b], 1);
    } else {
      pk[i] = 0xFFFFFFFFu;
    }
  }
  __syncthreads();

  int hv = (t < nbk) ? hist[t] : 0;
  sh[t] = hv;
  __syncthreads();
  for (int o = 1; o < 256; o <<= 1) {
    int u = (t >= o) ? sh[t - o] : 0;
    __syncthreads();
    sh[t] += u;
    __syncthreads();
  }
  if (t < nbk) {
    lbase[t] = sh[t] - hv;
    lcur[t] = sh[t] - hv;
    gpos[t] = hv ? atomicAdd(&bucket_cursor[t], hv) : 0;
  }
  __syncthreads();

#pragma unroll
  for (int i = 0; i < PT; i++) {
    if (pk[i] != 0xFFFFFFFFu) {
      int b = pk[i] >> 24;
      int lp = atomicAdd(&lcur[b], 1);
      stage[lp] = pk[i];
    }
  }
  __syncthreads();

  for (int i = t; i < cnt; i += 256) {
    unsigned int v = stage[i];
    int b = v >> 24;
    binned[gpos[b] + (i - lbase[b])] = v;
  }
}

template <int CAP>  // 12288
__global__ void build_kernel(const unsigned int* __restrict__ binned,
                             const int* __restrict__ bucket_base, int* __restrict__ offsets,
                             int* __restrict__ csr_src, int Nn, int Etot, int nbk) {
  __shared__ int nhist[256];
  __shared__ int sh[256];
  __shared__ int lcur[256];
  __shared__ unsigned short stage[CAP];
  int b = blockIdx.x;
  int t = threadIdx.x;
  int base = bucket_base[b];
  int sz = bucket_base[b + 1] - base;

  nhist[t] = 0;
  __syncthreads();
  for (int i = t; i < sz; i += 256) atomicAdd(&nhist[binned[base + i] & 255], 1);
  __syncthreads();

  int hv = nhist[t];
  sh[t] = hv;
  __syncthreads();
  for (int o = 1; o < 256; o <<= 1) {
    int u = (t >= o) ? sh[t - o] : 0;
    __syncthreads();
    sh[t] += u;
    __syncthreads();
  }
  int excl = sh[t] - hv;
  int node = (b << 8) + t;
  if (node < Nn) offsets[node] = base + excl;
  if (b == nbk - 1 && t == 0) offsets[Nn] = Etot;
  lcur[t] = excl;
  __syncthreads();

  if (sz <= CAP) {
    for (int i = t; i < sz; i += 256) {
      unsigned int v = binned[base + i];
      int lp = atomicAdd(&lcur[v & 255], 1);
      stage[lp] = (unsigned short)((v >> 8) & 0xFFFFu);
    }
    __syncthreads();
    for (int i = t; i < sz; i += 256) csr_src[base + i] = (int)stage[i];
  } else {
    for (int i = t; i < sz; i += 256) {
      unsigned int v = binned[base + i];
      int lp = atomicAdd(&lcur[v & 255], 1);
      csr_src[base + lp] = (int)((v >> 8) & 0xFFFFu);
    }
  }
}

// ---------------- GEMM + fused attention dots ----------------

template <int K, int NC, int ROWS, int H>
__global__ void gemm_att(const float* __restrict__ X, const float* __restrict__ W,
                         const float* __restrict__ att_s, const float* __restrict__ att_d,
                         float* __restrict__ Y, float* __restrict__ AS, float* __restrict__ AD,
                         int Nrows) {
  __shared__ float xs[ROWS * K];
  int r0 = blockIdx.x * ROWS;
  int t = threadIdx.x;
  int h = t >> 6;
  int lane = t & 63;

  const float4* X4 = (const float4*)(X + (size_t)r0 * K);
  float4* xs4 = (float4*)xs;
  for (int i = t; i < ROWS * K / 4; i += NC) xs4[i] = X4[i];
  __syncthreads();

  float acc[ROWS];
#pragma unroll
  for (int r = 0; r < ROWS; r++) acc[r] = 0.f;
  for (int k = 0; k < K; k++) {
    float w = W[k * NC + t];
#pragma unroll
    for (int r = 0; r < ROWS; r++) acc[r] = fmaf(xs[r * K + k], w, acc[r]);
  }

  float asw = att_s[t];
  float adw = att_d[t];
#pragma unroll
  for (int r = 0; r < ROWS; r++) {
    Y[(size_t)(r0 + r) * NC + t] = acc[r];
    float ps = acc[r] * asw;
    float pd = acc[r] * adw;
    for (int o = 32; o > 0; o >>= 1) {
      ps += __shfl_xor(ps, o);
      pd += __shfl_xor(pd, o);
    }
    if (lane == 0) {
      AS[(r0 + r) * H + h] = ps;
      AD[(r0 + r) * H + h] = pd;
    }
  }
}

// ---------------- node softmax + aggregate ----------------

// One block per node; wave = head; 4 groups of 16 lanes; 16 edges per unrolled
// iteration -> 4 independent dwordx4 gathers in flight per wave.
template <int H, bool RELU>
__global__ void node_kernel(const int* __restrict__ offsets, const int* __restrict__ csr_src,
                            const float* __restrict__ AS, const float* __restrict__ AD,
                            const float* __restrict__ XP, const float* __restrict__ bias,
                            float* __restrict__ OUT, int Nn) {
  constexpr int C = 64;
  constexpr int HC4 = H * C / 4;
  int n = blockIdx.x;
  int h = threadIdx.x >> 6;
  int lane = threadIdx.x & 63;
  int g = lane >> 4;
  int sub = lane & 15;

  int beg = offsets[n], end = offsets[n + 1];
  int deg = end - beg;

  float ad_n = AD[n * H + h];
  const float4* XP4 = (const float4*)XP + (h * 16 + sub);  // pre-offset base

  float4 a0 = make_float4(0.f, 0.f, 0.f, 0.f);
  float4 a1 = make_float4(0.f, 0.f, 0.f, 0.f);
  float4 a2 = make_float4(0.f, 0.f, 0.f, 0.f);
  float4 a3 = make_float4(0.f, 0.f, 0.f, 0.f);
  float z = 0.f;

  float e_self = __expf(lrelu(AS[n * H + h] + ad_n));
  if (g == 0) {
    float4 v = XP4[(size_t)n * HC4];
    a0.x = e_self * v.x; a0.y = e_self * v.y; a0.z = e_self * v.z; a0.w = e_self * v.w;
  }
  if (lane == 0) z = e_self;

  for (int i0 = 0; i0 < deg; i0 += 64) {
    int cnt = min(64, deg - i0);
    int srcv = 0;
    float ev = 0.f;
    if (lane < cnt) {
      srcv = csr_src[beg + i0 + lane];
      ev = __expf(lrelu(AS[srcv * H + h] + ad_n));
    }
    z += ev;
    int j = 0;
    // 16 edges / iter: 4 independent loads in flight
    for (; j + 16 <= cnt; j += 16) {
      int s0 = __shfl(srcv, j + g), s1 = __shfl(srcv, j + 4 + g);
      int s2 = __shfl(srcv, j + 8 + g), s3 = __shfl(srcv, j + 12 + g);
      float e0 = __shfl(ev, j + g), e1 = __shfl(ev, j + 4 + g);
      float e2 = __shfl(ev, j + 8 + g), e3 = __shfl(ev, j + 12 + g);
      float4 v0 = XP4[(size_t)s0 * HC4];
      float4 v1 = XP4[(size_t)s1 * HC4];
      float4 v2 = XP4[(size_t)s2 * HC4];
      float4 v3 = XP4[(size_t)s3 * HC4];
      a0.x = fmaf(e0, v0.x, a0.x); a0.y = fmaf(e0, v0.y, a0.y);
      a0.z = fmaf(e0, v0.z, a0.z); a0.w = fmaf(e0, v0.w, a0.w);
      a1.x = fmaf(e1, v1.x, a1.x); a1.y = fmaf(e1, v1.y, a1.y);
      a1.z = fmaf(e1, v1.z, a1.z); a1.w = fmaf(e1, v1.w, a1.w);
      a2.x = fmaf(e2, v2.x, a2.x); a2.y = fmaf(e2, v2.y, a2.y);
      a2.z = fmaf(e2, v2.z, a2.z); a2.w = fmaf(e2, v2.w, a2.w);
      a3.x = fmaf(e3, v3.x, a3.x); a3.y = fmaf(e3, v3.y, a3.y);
      a3.z = fmaf(e3, v3.z, a3.z); a3.w = fmaf(e3, v3.w, a3.w);
    }
    for (; j + 4 <= cnt; j += 4) {
      int s = __shfl(srcv, j + g);
      float e = __shfl(ev, j + g);
      float4 v = XP4[(size_t)s * HC4];
      a0.x = fmaf(e, v.x, a0.x); a0.y = fmaf(e, v.y, a0.y);
      a0.z = fmaf(e, v.z, a0.z); a0.w = fmaf(e, v.w, a0.w);
    }
    if (j < cnt) {  // wave-uniform branch; 1..3 remainder edges
      int idx = j + g;
      int s = __shfl(srcv, idx & 63);
      float e = __shfl(ev, idx & 63);
      if (idx < cnt) {
        float4 v = XP4[(size_t)s * HC4];
        a0.x = fmaf(e, v.x, a0.x); a0.y = fmaf(e, v.y, a0.y);
        a0.z = fmaf(e, v.z, a0.z); a0.w = fmaf(e, v.w, a0.w);
      }
    }
  }

  float4 acc;
  acc.x = (a0.x + a1.x) + (a2.x + a3.x);
  acc.y = (a0.y + a1.y) + (a2.y + a3.y);
  acc.z = (a0.z + a1.z) + (a2.z + a3.z);
  acc.w = (a0.w + a1.w) + (a2.w + a3.w);

#pragma unroll
  for (int o = 32; o >= 16; o >>= 1) {
    acc.x += __shfl_xor(acc.x, o);
    acc.y += __shfl_xor(acc.y, o);
    acc.z += __shfl_xor(acc.z, o);
    acc.w += __shfl_xor(acc.w, o);
  }
  for (int o = 32; o > 0; o >>= 1) z += __shfl_xor(z, o);
  float inv = 1.0f / z;

  if (g == 0) {
    float4 b4 = ((const float4*)bias)[h * 16 + sub];
    float4 r;
    r.x = fmaf(acc.x, inv, b4.x);
    r.y = fmaf(acc.y, inv, b4.y);
    r.z = fmaf(acc.z, inv, b4.z);
    r.w = fmaf(acc.w, inv, b4.w);
    if (RELU) {
      r.x = fmaxf(r.x, 0.f); r.y = fmaxf(r.y, 0.f);
      r.z = fmaxf(r.z, 0.f); r.w = fmaxf(r.w, 0.f);
    }
    ((float4*)OUT)[(size_t)n * HC4 + h * 16 + sub] = r;
  }
}

// ---------------- launch ----------------

static inline size_t alignup(size_t x) { return (x + 255) & ~(size_t)255; }

extern "C" void kernel_launch(void* const* d_in, const int* in_sizes, int n_in,
                              void* d_out, int out_size, void* d_ws, size_t ws_size,
                              hipStream_t stream) {
  const float* x    = (const float*)d_in[0];
  const int*   edges= (const int*)d_in[1];
  const float* W1   = (const float*)d_in[2];
  const float* as1w = (const float*)d_in[3];
  const float* ad1w = (const float*)d_in[4];
  const float* b1   = (const float*)d_in[5];
  const float* W2   = (const float*)d_in[6];
  const float* as2w = (const float*)d_in[7];
  const float* ad2w = (const float*)d_in[8];
  const float* b2   = (const float*)d_in[9];

  const int N = in_sizes[0] / 128;   // 50000
  const int E = in_sizes[1] / 2;     // 1600000
  const int* src = edges;
  const int* dst = edges + E;
  const int nbk = (N + 255) >> 8;    // 196 buckets

  char* p = (char*)d_ws;
  size_t off = 0;
  auto take = [&](size_t bytes) { char* r = p + off; off = alignup(off + bytes); return r; };
  float* xp1   = (float*)take((size_t)N * 128 * 4);
  float* hbuf  = (float*)take((size_t)N * 128 * 4);
  float* xp2   = (float*)take((size_t)N * 64 * 4);
  float* as1   = (float*)take((size_t)N * 2 * 4);
  float* ad1   = (float*)take((size_t)N * 2 * 4);
  float* as2   = (float*)take((size_t)N * 4);
  float* ad2   = (float*)take((size_t)N * 4);
  int* offsets = (int*)take((size_t)(N + 1) * 4);
  int* csr_src = (int*)take((size_t)E * 4);
  unsigned int* binned = (unsigned int*)take((size_t)E * 4);
  int* bcount  = (int*)take((size_t)(nbk + 1) * 4);
  int* bbase   = (int*)take((size_t)(nbk + 1) * 4);
  int* bcursor = (int*)take((size_t)(nbk + 1) * 4);
  (void)ws_size;

  constexpr int CHUNK = 8192;
  const int binBlocks = (E + CHUNK - 1) / CHUNK;

  zero_small<<<1, 256, 0, stream>>>(bcount, nbk);
  bucket_hist<<<392, 256, 0, stream>>>(dst, bcount, E, nbk);
  bucket_scan<<<1, 256, 0, stream>>>(bcount, bbase, bcursor, nbk, E);
  bin_kernel<CHUNK><<<binBlocks, 256, 0, stream>>>(src, dst, bcursor, binned, E, nbk);
  build_kernel<12288><<<nbk, 256, 0, stream>>>(binned, bbase, offsets, csr_src, N, E, nbk);

  gemm_att<128, 128, 16, 2><<<N / 16, 128, 0, stream>>>(x, W1, as1w, ad1w, xp1, as1, ad1, N);
  node_kernel<2, true><<<N, 128, 0, stream>>>(offsets, csr_src, as1, ad1, xp1, b1, hbuf, N);

  gemm_att<128, 64, 16, 1><<<N / 16, 64, 0, stream>>>(hbuf, W2, as2w, ad2w, xp2, as2, ad2, N);
  node_kernel<1, false><<<N, 64, 0, stream>>>(offsets, csr_src, as2, ad2, xp2, b2, (float*)d_out, N);
}

// Round 5
// 229.643 us; speedup vs baseline: 2.1852x; 1.2940x over previous
//
#include <hip/hip_runtime.h>
#include <hip/hip_bf16.h>
#include <hip/hip_fp16.h>

// GAT 2-layer forward for MI355X — round 5.
// Change vs round 4: gather path moved to fp16. r4's null MLP result showed the
// node_kernel is throughput-bound on the L2-miss path (~3.8 TB/s regardless of
// unrolling), so the lever is bytes: projected features are stored fp16-only
// (12.8/6.4 MB), gathered as 8 lanes x dwordx4 per edge (128 B/row), fp32
// accumulation and fp32 attention logits (softmax weights exact).

#define SLOPE 0.2f
static __device__ __forceinline__ float lrelu(float a) { return a > 0.f ? a : SLOPE * a; }

#define NBK_MAX 256  // max buckets (N <= 65536)

// ---------------- CSR build (bucketed) ----------------

__global__ void zero_small(int* __restrict__ p, int n) {
  int i = blockIdx.x * blockDim.x + threadIdx.x;
  if (i < n) p[i] = 0;
}

__global__ void bucket_hist(const int* __restrict__ dst, int* __restrict__ bucket_count,
                            int E, int nbk) {
  __shared__ int h[NBK_MAX];
  for (int i = threadIdx.x; i < nbk; i += blockDim.x) h[i] = 0;
  __syncthreads();
  int stride = gridDim.x * blockDim.x;
  for (int e = blockIdx.x * blockDim.x + threadIdx.x; e < E; e += stride)
    atomicAdd(&h[dst[e] >> 8], 1);
  __syncthreads();
  for (int i = threadIdx.x; i < nbk; i += blockDim.x)
    if (h[i]) atomicAdd(&bucket_count[i], h[i]);
}

__global__ void bucket_scan(const int* __restrict__ bucket_count, int* __restrict__ bucket_base,
                            int* __restrict__ bucket_cursor, int nbk, int Etot) {
  __shared__ int sh[256];
  int t = threadIdx.x;
  int v = (t < nbk) ? bucket_count[t] : 0;
  sh[t] = v;
  __syncthreads();
  for (int o = 1; o < 256; o <<= 1) {
    int u = (t >= o) ? sh[t - o] : 0;
    __syncthreads();
    sh[t] += u;
    __syncthreads();
  }
  int excl = sh[t] - v;
  if (t < nbk) { bucket_base[t] = excl; bucket_cursor[t] = excl; }
  if (t == 0) bucket_base[nbk] = Etot;
}

template <int CHUNK>  // 8192 = 256 threads x 32
__global__ void bin_kernel(const int* __restrict__ src, const int* __restrict__ dst,
                           int* __restrict__ bucket_cursor, unsigned int* __restrict__ binned,
                           int E, int nbk) {
  constexpr int PT = CHUNK / 256;
  __shared__ int hist[NBK_MAX];
  __shared__ int lbase[NBK_MAX];
  __shared__ int lcur[NBK_MAX];
  __shared__ int gpos[NBK_MAX];
  __shared__ unsigned int stage[CHUNK];
  __shared__ int sh[256];
  int t = threadIdx.x;
  int e0 = blockIdx.x * CHUNK;
  int cnt = min(CHUNK, E - e0);

  for (int i = t; i < nbk; i += 256) hist[i] = 0;
  __syncthreads();

  unsigned int pk[PT];
#pragma unroll
  for (int i = 0; i < PT; i++) {
    int e = e0 + t + i * 256;
    if (e < E) {
      int s = src[e], d = dst[e];
      int b = d >> 8;
      pk[i] = ((unsigned)b << 24) | ((unsigned)s << 8) | (unsigned)(d & 255);
      atomicAdd(&hist[b], 1);
    } else {
      pk[i] = 0xFFFFFFFFu;
    }
  }
  __syncthreads();

  int hv = (t < nbk) ? hist[t] : 0;
  sh[t] = hv;
  __syncthreads();
  for (int o = 1; o < 256; o <<= 1) {
    int u = (t >= o) ? sh[t - o] : 0;
    __syncthreads();
    sh[t] += u;
    __syncthreads();
  }
  if (t < nbk) {
    lbase[t] = sh[t] - hv;
    lcur[t] = sh[t] - hv;
    gpos[t] = hv ? atomicAdd(&bucket_cursor[t], hv) : 0;
  }
  __syncthreads();

#pragma unroll
  for (int i = 0; i < PT; i++) {
    if (pk[i] != 0xFFFFFFFFu) {
      int b = pk[i] >> 24;
      int lp = atomicAdd(&lcur[b], 1);
      stage[lp] = pk[i];
    }
  }
  __syncthreads();

  for (int i = t; i < cnt; i += 256) {
    unsigned int v = stage[i];
    int b = v >> 24;
    binned[gpos[b] + (i - lbase[b])] = v;
  }
}

template <int CAP>  // 12288
__global__ void build_kernel(const unsigned int* __restrict__ binned,
                             const int* __restrict__ bucket_base, int* __restrict__ offsets,
                             int* __restrict__ csr_src, int Nn, int Etot, int nbk) {
  __shared__ int nhist[256];
  __shared__ int sh[256];
  __shared__ int lcur[256];
  __shared__ unsigned short stage[CAP];
  int b = blockIdx.x;
  int t = threadIdx.x;
  int base = bucket_base[b];
  int sz = bucket_base[b + 1] - base;

  nhist[t] = 0;
  __syncthreads();
  for (int i = t; i < sz; i += 256) atomicAdd(&nhist[binned[base + i] & 255], 1);
  __syncthreads();

  int hv = nhist[t];
  sh[t] = hv;
  __syncthreads();
  for (int o = 1; o < 256; o <<= 1) {
    int u = (t >= o) ? sh[t - o] : 0;
    __syncthreads();
    sh[t] += u;
    __syncthreads();
  }
  int excl = sh[t] - hv;
  int node = (b << 8) + t;
  if (node < Nn) offsets[node] = base + excl;
  if (b == nbk - 1 && t == 0) offsets[Nn] = Etot;
  lcur[t] = excl;
  __syncthreads();

  if (sz <= CAP) {
    for (int i = t; i < sz; i += 256) {
      unsigned int v = binned[base + i];
      int lp = atomicAdd(&lcur[v & 255], 1);
      stage[lp] = (unsigned short)((v >> 8) & 0xFFFFu);
    }
    __syncthreads();
    for (int i = t; i < sz; i += 256) csr_src[base + i] = (int)stage[i];
  } else {
    for (int i = t; i < sz; i += 256) {
      unsigned int v = binned[base + i];
      int lp = atomicAdd(&lcur[v & 255], 1);
      csr_src[base + lp] = (int)((v >> 8) & 0xFFFFu);
    }
  }
}

// ---------------- GEMM + fused attention dots (fp16 feature output) ----------------

template <int K, int NC, int ROWS, int H>
__global__ void gemm_att(const float* __restrict__ X, const float* __restrict__ W,
                         const float* __restrict__ att_s, const float* __restrict__ att_d,
                         __half* __restrict__ YH, float* __restrict__ AS, float* __restrict__ AD,
                         int Nrows) {
  __shared__ float xs[ROWS * K];
  int r0 = blockIdx.x * ROWS;
  int t = threadIdx.x;
  int h = t >> 6;
  int lane = t & 63;

  const float4* X4 = (const float4*)(X + (size_t)r0 * K);
  float4* xs4 = (float4*)xs;
  for (int i = t; i < ROWS * K / 4; i += NC) xs4[i] = X4[i];
  __syncthreads();

  float acc[ROWS];
#pragma unroll
  for (int r = 0; r < ROWS; r++) acc[r] = 0.f;
  for (int k = 0; k < K; k++) {
    float w = W[k * NC + t];
#pragma unroll
    for (int r = 0; r < ROWS; r++) acc[r] = fmaf(xs[r * K + k], w, acc[r]);
  }

  float asw = att_s[t];
  float adw = att_d[t];
#pragma unroll
  for (int r = 0; r < ROWS; r++) {
    YH[(size_t)(r0 + r) * NC + t] = __float2half(acc[r]);
    float ps = acc[r] * asw;
    float pd = acc[r] * adw;
    for (int o = 32; o > 0; o >>= 1) {
      ps += __shfl_xor(ps, o);
      pd += __shfl_xor(pd, o);
    }
    if (lane == 0) {
      AS[(r0 + r) * H + h] = ps;
      AD[(r0 + r) * H + h] = pd;
    }
  }
}

// ---------------- node softmax + aggregate ----------------

static __device__ __forceinline__ void fma8(uint4 u, float e, float* __restrict__ acc) {
  float2 f0 = __half22float2(*(const __half2*)&u.x);
  float2 f1 = __half22float2(*(((const __half2*)&u.x) + 1));
  float2 f2 = __half22float2(*(const __half2*)&u.z);
  float2 f3 = __half22float2(*(((const __half2*)&u.z) + 1));
  acc[0] = fmaf(e, f0.x, acc[0]); acc[1] = fmaf(e, f0.y, acc[1]);
  acc[2] = fmaf(e, f1.x, acc[2]); acc[3] = fmaf(e, f1.y, acc[3]);
  acc[4] = fmaf(e, f2.x, acc[4]); acc[5] = fmaf(e, f2.y, acc[5]);
  acc[6] = fmaf(e, f3.x, acc[6]); acc[7] = fmaf(e, f3.y, acc[7]);
}

// One block per node; wave = head; 8 groups of 8 lanes; each lane owns 8
// channels (one dwordx4 of fp16). 32 edges per unrolled iter = 4 loads in flight.
template <int H, bool RELU>
__global__ void node_kernel(const int* __restrict__ offsets, const int* __restrict__ csr_src,
                            const float* __restrict__ AS, const float* __restrict__ AD,
                            const __half* __restrict__ XPH, const float* __restrict__ bias,
                            float* __restrict__ OUT, int Nn) {
  constexpr int C = 64;
  constexpr int ROWH = H * C;  // halfs per feature row
  int n = blockIdx.x;
  int h = threadIdx.x >> 6;
  int lane = threadIdx.x & 63;
  int g = lane >> 3;   // edge group 0..7
  int sub = lane & 7;  // channel block (8 halfs = 16 B)

  int beg = offsets[n], end = offsets[n + 1];
  int deg = end - beg;

  float ad_n = AD[n * H + h];
  const __half* base = XPH + h * C + sub * 8;  // per-lane channel base

  float acc[8];
#pragma unroll
  for (int k = 0; k < 8; k++) acc[k] = 0.f;
  float z = 0.f;

  float e_self = __expf(lrelu(AS[n * H + h] + ad_n));
  if (g == 0) {
    uint4 u = *(const uint4*)(base + (size_t)n * ROWH);
    fma8(u, e_self, acc);
  }
  if (lane == 0) z = e_self;

  for (int i0 = 0; i0 < deg; i0 += 64) {
    int cnt = min(64, deg - i0);
    int srcv = 0;
    float ev = 0.f;
    if (lane < cnt) {
      srcv = csr_src[beg + i0 + lane];
      ev = __expf(lrelu(AS[srcv * H + h] + ad_n));
    }
    z += ev;
    int j = 0;
    // 32 edges / iter: 4 independent dwordx4 gathers in flight
    for (; j + 32 <= cnt; j += 32) {
      int s0 = __shfl(srcv, j + g),      s1 = __shfl(srcv, j + 8 + g);
      int s2 = __shfl(srcv, j + 16 + g), s3 = __shfl(srcv, j + 24 + g);
      float e0 = __shfl(ev, j + g),      e1 = __shfl(ev, j + 8 + g);
      float e2 = __shfl(ev, j + 16 + g), e3 = __shfl(ev, j + 24 + g);
      uint4 u0 = *(const uint4*)(base + (size_t)s0 * ROWH);
      uint4 u1 = *(const uint4*)(base + (size_t)s1 * ROWH);
      uint4 u2 = *(const uint4*)(base + (size_t)s2 * ROWH);
      uint4 u3 = *(const uint4*)(base + (size_t)s3 * ROWH);
      fma8(u0, e0, acc);
      fma8(u1, e1, acc);
      fma8(u2, e2, acc);
      fma8(u3, e3, acc);
    }
    for (; j + 8 <= cnt; j += 8) {
      int s = __shfl(srcv, j + g);
      float e = __shfl(ev, j + g);
      uint4 u = *(const uint4*)(base + (size_t)s * ROWH);
      fma8(u, e, acc);
    }
    if (j < cnt) {  // 1..7 remainder edges (wave-uniform outer branch)
      int idx = j + g;
      int s = __shfl(srcv, idx & 63);
      float e = __shfl(ev, idx & 63);
      if (idx < cnt) {
        uint4 u = *(const uint4*)(base + (size_t)s * ROWH);
        fma8(u, e, acc);
      }
    }
  }

  // reduce across the 8 edge groups (lane bits 3..5), keeping sub
#pragma unroll
  for (int o = 8; o <= 32; o <<= 1) {
#pragma unroll
    for (int k = 0; k < 8; k++) acc[k] += __shfl_xor(acc[k], o);
  }
  for (int o = 32; o > 0; o >>= 1) z += __shfl_xor(z, o);
  float inv = 1.0f / z;

  if (g == 0) {
    const float* bp = bias + h * C + sub * 8;
    float* op = OUT + (size_t)n * ROWH + h * C + sub * 8;
    float4 r0, r1;
    r0.x = fmaf(acc[0], inv, bp[0]); r0.y = fmaf(acc[1], inv, bp[1]);
    r0.z = fmaf(acc[2], inv, bp[2]); r0.w = fmaf(acc[3], inv, bp[3]);
    r1.x = fmaf(acc[4], inv, bp[4]); r1.y = fmaf(acc[5], inv, bp[5]);
    r1.z = fmaf(acc[6], inv, bp[6]); r1.w = fmaf(acc[7], inv, bp[7]);
    if (RELU) {
      r0.x = fmaxf(r0.x, 0.f); r0.y = fmaxf(r0.y, 0.f);
      r0.z = fmaxf(r0.z, 0.f); r0.w = fmaxf(r0.w, 0.f);
      r1.x = fmaxf(r1.x, 0.f); r1.y = fmaxf(r1.y, 0.f);
      r1.z = fmaxf(r1.z, 0.f); r1.w = fmaxf(r1.w, 0.f);
    }
    ((float4*)op)[0] = r0;
    ((float4*)op)[1] = r1;
  }
}

// ---------------- launch ----------------

static inline size_t alignup(size_t x) { return (x + 255) & ~(size_t)255; }

extern "C" void kernel_launch(void* const* d_in, const int* in_sizes, int n_in,
                              void* d_out, int out_size, void* d_ws, size_t ws_size,
                              hipStream_t stream) {
  const float* x    = (const float*)d_in[0];
  const int*   edges= (const int*)d_in[1];
  const float* W1   = (const float*)d_in[2];
  const float* as1w = (const float*)d_in[3];
  const float* ad1w = (const float*)d_in[4];
  const float* b1   = (const float*)d_in[5];
  const float* W2   = (const float*)d_in[6];
  const float* as2w = (const float*)d_in[7];
  const float* ad2w = (const float*)d_in[8];
  const float* b2   = (const float*)d_in[9];

  const int N = in_sizes[0] / 128;   // 50000
  const int E = in_sizes[1] / 2;     // 1600000
  const int* src = edges;
  const int* dst = edges + E;
  const int nbk = (N + 255) >> 8;    // 196 buckets

  char* p = (char*)d_ws;
  size_t off = 0;
  auto take = [&](size_t bytes) { char* r = p + off; off = alignup(off + bytes); return r; };
  __half* xph1 = (__half*)take((size_t)N * 128 * 2);
  __half* xph2 = (__half*)take((size_t)N * 64 * 2);
  float* hbuf  = (float*)take((size_t)N * 128 * 4);
  float* as1   = (float*)take((size_t)N * 2 * 4);
  float* ad1   = (float*)take((size_t)N * 2 * 4);
  float* as2   = (float*)take((size_t)N * 4);
  float* ad2   = (float*)take((size_t)N * 4);
  int* offsets = (int*)take((size_t)(N + 1) * 4);
  int* csr_src = (int*)take((size_t)E * 4);
  unsigned int* binned = (unsigned int*)take((size_t)E * 4);
  int* bcount  = (int*)take((size_t)(nbk + 1) * 4);
  int* bbase   = (int*)take((size_t)(nbk + 1) * 4);
  int* bcursor = (int*)take((size_t)(nbk + 1) * 4);
  (void)ws_size;

  constexpr int CHUNK = 8192;
  const int binBlocks = (E + CHUNK - 1) / CHUNK;

  zero_small<<<1, 256, 0, stream>>>(bcount, nbk);
  bucket_hist<<<392, 256, 0, stream>>>(dst, bcount, E, nbk);
  bucket_scan<<<1, 256, 0, stream>>>(bcount, bbase, bcursor, nbk, E);
  bin_kernel<CHUNK><<<binBlocks, 256, 0, stream>>>(src, dst, bcursor, binned, E, nbk);
  build_kernel<12288><<<nbk, 256, 0, stream>>>(binned, bbase, offsets, csr_src, N, E, nbk);

  // layer 1 (H=2, C=64, ReLU)
  gemm_att<128, 128, 16, 2><<<N / 16, 128, 0, stream>>>(x, W1, as1w, ad1w, xph1, as1, ad1, N);
  node_kernel<2, true><<<N, 128, 0, stream>>>(offsets, csr_src, as1, ad1, xph1, b1, hbuf, N);

  // layer 2 (H=1, C=64)
  gemm_att<128, 64, 16, 1><<<N / 16, 64, 0, stream>>>(hbuf, W2, as2w, ad2w, xph2, as2, ad2, N);
  node_kernel<1, false><<<N, 64, 0, stream>>>(offsets, csr_src, as2, ad2, xph2, b2, (float*)d_out, N);
}